// Round 15
// baseline (147.216 us; speedup 1.0000x reference)
//
#include <hip/hip_runtime.h>

#define B_   2048
#define T1_  31
#define D_   128
#define MB_  8

typedef __attribute__((ext_vector_type(8))) short bf16x8;
typedef __attribute__((ext_vector_type(4))) float f32x4;
typedef __attribute__((ext_vector_type(2))) float f32x2;

__device__ __forceinline__ unsigned cvt_pk_bf16(float lo, float hi) {
    unsigned r;
    asm("v_cvt_pk_bf16_f32 %0, %1, %2" : "=v"(r) : "v"(lo), "v"(hi));
    return r;
}
__device__ __forceinline__ float rcpf_(float x) { return __builtin_amdgcn_rcpf(x); }
__device__ __forceinline__ float sigf(float x)  { return rcpf_(1.0f + __expf(-x)); }
__device__ __forceinline__ float tanhf_(float x) {
    float ax = fabsf(x);
    float t  = 1.0f - 2.0f * rcpf_(__expf(2.0f * ax) + 1.0f);
    return copysignf(t, x);
}

#define BAR_LDS() asm volatile("s_waitcnt lgkmcnt(0)\n\ts_barrier" ::: "memory")

// NOBAR=1: barrier-free probe (racy; measures self-paced per-wave loop time).
// PASSES: loop repetitions for probe amplification. Real kernel = <0,1>.
template<int NOBAR, int PASSES>
__global__ __launch_bounds__(512, 2) void enc_k(
    const float* __restrict__ in,    // [B][31][128]
    const float* __restrict__ Wih,   // [512][128]
    const float* __restrict__ Whh,   // [512][128]
    const float* __restrict__ bih,   // [512]
    const float* __restrict__ bhh,   // [512]
    const float* __restrict__ aw,    // [287]
    float* __restrict__ outW,        // [B][31][128]
    float* __restrict__ outE)        // [B][31][128]
{
    const int tid  = threadIdx.x;
    const int lane = tid & 63;
    const int wv   = tid >> 6;        // wave 0..7
    const int b0   = blockIdx.x * MB_;
    const int l15  = lane & 15;
    const int lq   = lane >> 4;

    __shared__ __align__(16) char Xw[30 * MB_ * 256];   // wx slots, 61440 B
    __shared__ __align__(16) char Hs[2 * MB_ * 256];    // h dbuf, 4096 B

    // ---------------- weight fragments -> registers ----------------------------
    bf16x8 bw[4][8];
    #pragma unroll
    for (int s = 0; s < 4; ++s) {
        int n = s * 128 + wv * 16 + l15;
        #pragma unroll
        for (int kf = 0; kf < 8; ++kf) {
            int kb = kf * 32 + lq * 8;
            const float* wp = (kf < 4) ? (Wih + n * D_ + kb) : (Whh + n * D_ + (kb - 128));
            float4 fa = *(const float4*)(wp);
            float4 fb = *(const float4*)(wp + 4);
            union { bf16x8 v; unsigned u[4]; } tmp;
            tmp.u[0] = cvt_pk_bf16(fa.x, fa.y);
            tmp.u[1] = cvt_pk_bf16(fa.z, fa.w);
            tmp.u[2] = cvt_pk_bf16(fb.x, fb.y);
            tmp.u[3] = cvt_pk_bf16(fb.z, fb.w);
            bw[s][kf] = tmp.v;
        }
    }
    const int col = wv * 16 + l15;
    const float bsv[4] = { bih[col]         + bhh[col],
                           bih[128 + col]   + bhh[128 + col],
                           bih[256 + col]   + bhh[256 + col],
                           bih[384 + col]   + bhh[384 + col] };

    // ---------------- pre-phase: x_score + pure-shfl softmax (row == wave) -----
    const int mg = wv;
    const int d0 = 2 * lane;
    const float* pin = in + (size_t)(b0 + mg) * (T1_ * D_) + d0;

    float2 xc[T1_];                    // input column-pair cached in registers
    float xs0 = 0.f, xs1 = 0.f;
    #pragma unroll
    for (int t = 0; t < T1_; ++t) {
        float wt = aw[2 * D_ + t];
        xc[t] = *(const float2*)(pin + t * D_);
        xs0 = fmaf(wt, xc[t].x, xs0);
        xs1 = fmaf(wt, xc[t].y, xs1);
    }
    float mx = fmaxf(xs0, xs1);
    #pragma unroll
    for (int o = 32; o > 0; o >>= 1) mx = fmaxf(mx, __shfl_xor(mx, o));
    float e0 = __expf(xs0 - mx), e1 = __expf(xs1 - mx);
    float ss = e0 + e1;
    #pragma unroll
    for (int o = 32; o > 0; o >>= 1) ss += __shfl_xor(ss, o);
    float inv = 1.0f / ss;
    const float a0 = e0 * inv;
    const float a1 = e1 * inv;

    // ---------------- wx staging: outW (NT) + Xw (swizzled bf16) ---------------
    const int wxbyte = (4 * lane) ^ (mg << 4);
    float* outWp = outW + (size_t)(b0 + mg) * (T1_ * D_) + d0;
    unsigned wx30 = 0;
    #pragma unroll
    for (int t = 0; t < T1_; ++t) {
        float w0 = a0 * xc[t].x, w1 = a1 * xc[t].y;
        f32x2 wsv; wsv[0] = w0; wsv[1] = w1;
        __builtin_nontemporal_store(wsv, (f32x2*)(outWp + t * D_));
        unsigned u = cvt_pk_bf16(w0, w1);
        if (t < 30) *(unsigned*)(Xw + t * 2048 + mg * 256 + wxbyte) = u;
        else        wx30 = u;
    }
    ((unsigned*)Hs)[tid]       = 0u;   // h(0) = 0, both buffers
    ((unsigned*)Hs)[tid + 512] = 0u;
    BAR_LDS();                         // staging visible; global stores in flight

    // ---------------- recurrent loop -------------------------------------------
    const int arow = l15 & 7;          // A-frag row (rows 8-15 replicate 0-7)
    const int asw  = arow << 4;
    const int rb   = ((lane & 31) >> 4) * 4 + ((lane >> 5) << 1);
    const bool hi32 = (lane >= 32);
    float* outE0 = outE + (size_t)(b0 + rb)     * (T1_ * D_) + col;
    float* outE1 = outE + (size_t)(b0 + rb + 1) * (T1_ * D_) + col;

    #pragma unroll 1
    for (int pass = 0; pass < PASSES; ++pass) {
        float cs0 = 0.f, cs1 = 0.f;
        f32x4 accx[4];
        bf16x8 wxn[4];
        {   // prologue: accx for t=0; issue wxn = frags(t=1)
            bf16x8 w0[4];
            #pragma unroll
            for (int kf = 0; kf < 4; ++kf)
                w0[kf] = *(const bf16x8*)(Xw + arow * 256 + ((kf * 64 + lq * 16) ^ asw));
            #pragma unroll
            for (int s = 0; s < 4; ++s) {
                float b = bsv[s];
                f32x4 aA = {b, b, b, b};
                #pragma unroll
                for (int kf = 0; kf < 4; ++kf)
                    aA = __builtin_amdgcn_mfma_f32_16x16x32_bf16(w0[kf], bw[s][kf], aA, 0, 0, 0);
                accx[s] = aA;
            }
            #pragma unroll
            for (int kf = 0; kf < 4; ++kf)
                wxn[kf] = *(const bf16x8*)(Xw + 2048 + arow * 256 + ((kf * 64 + lq * 16) ^ asw));
        }

        for (int t = 0; t < T1_; ++t) {
            // h fragments for this step
            const char* hp = Hs + (t & 1) * 2048 + arow * 256;
            bf16x8 hfr[4];
            #pragma unroll
            for (int kf = 0; kf < 4; ++kf)
                hfr[kf] = *(const bf16x8*)(hp + ((kf * 64 + lq * 16) ^ asw));

            // gates = accx(t) [carried] + h @ Whh^T (4-deep seeded chain, R8-proven)
            f32x4 acc[4];
            #pragma unroll
            for (int s = 0; s < 4; ++s) {
                f32x4 a_ = accx[s];
                #pragma unroll
                for (int kf = 0; kf < 4; ++kf)
                    a_ = __builtin_amdgcn_mfma_f32_16x16x32_bf16(hfr[kf], bw[s][4 + kf], a_, 0, 0, 0);
                acc[s] = a_;
            }

            // depth-2 prefetch: issue frags(t+2) ds_reads (drain during EW below)
            bf16x8 wxn2[4];
            if (t < 29) {
                int slot = (t + 2 == 30) ? 0 : (t + 2);
                const char* wn = Xw + slot * 2048 + arow * 256;
                #pragma unroll
                for (int kf = 0; kf < 4; ++kf)
                    wxn2[kf] = *(const bf16x8*)(wn + ((kf * 64 + lq * 16) ^ asw));
            }
            if (t == 1)   // recycle slot 0 with wx[30]; t=0 reads done at barrier(0)
                *(unsigned*)(Xw + mg * 256 + wxbyte) = wx30;

            // accx(t+1): wxn is already resident (no lgkm wait) -> MFMA latency
            // hides under the elementwise VALU work that follows.
            if (t < 30) {
                #pragma unroll
                for (int s = 0; s < 4; ++s) {
                    float b = bsv[s];
                    f32x4 aA = {b, b, b, b};
                    #pragma unroll
                    for (int kf = 0; kf < 4; ++kf)
                        aA = __builtin_amdgcn_mfma_f32_16x16x32_bf16(wxn[kf], bw[s][kf], aA, 0, 0, 0);
                    accx[s] = aA;
                }
            }

            // row select via replication
            float gq0[4], gq1[4];
            #pragma unroll
            for (int s = 0; s < 4; ++s) {
                gq0[s] = hi32 ? acc[s][2] : acc[s][0];
                gq1[s] = hi32 ? acc[s][3] : acc[s][1];
            }

            // elementwise, two independent cells interleaved
            float sf0 = sigf(gq0[1]), sf1 = sigf(gq1[1]);
            float si0 = sigf(gq0[0]), si1 = sigf(gq1[0]);
            float tg0 = tanhf_(gq0[2]), tg1 = tanhf_(gq1[2]);
            float so0 = sigf(gq0[3]), so1 = sigf(gq1[3]);
            float cn0 = sf0 * cs0 + si0 * tg0;  cs0 = cn0;
            float cn1 = sf1 * cs1 + si1 * tg1;  cs1 = cn1;
            float hh0 = so0 * tanhf_(cn0);
            float hh1 = so1 * tanhf_(cn1);
            unsigned hu = cvt_pk_bf16(hh0, hh1);

            // h LDS write (gates barrier); global NT stores after (don't gate)
            if (t < 30) {
                char* hw = Hs + ((t + 1) & 1) * 2048;
                *(unsigned short*)(hw + rb * 256       + ((2 * col) ^ (rb << 4)))       = (unsigned short)(hu & 0xffffu);
                *(unsigned short*)(hw + (rb + 1) * 256 + ((2 * col) ^ ((rb + 1) << 4))) = (unsigned short)(hu >> 16);
            }
            __builtin_nontemporal_store(hh0, outE0 + t * D_);
            __builtin_nontemporal_store(hh1, outE1 + t * D_);

            if (t < 29) {
                #pragma unroll
                for (int kf = 0; kf < 4; ++kf) wxn[kf] = wxn2[kf];
            }

            if constexpr (!NOBAR) BAR_LDS();
            else asm volatile("" ::: "memory");   // probe: no barrier, free-running
        }
    }
}

extern "C" void kernel_launch(void* const* d_in, const int* in_sizes, int n_in,
                              void* d_out, int out_size, void* d_ws, size_t ws_size,
                              hipStream_t stream) {
    const float* in  = (const float*)d_in[0];
    const float* Wih = (const float*)d_in[1];
    const float* Whh = (const float*)d_in[2];
    const float* bih = (const float*)d_in[3];
    const float* bhh = (const float*)d_in[4];
    const float* aw  = (const float*)d_in[5];

    float* outW = (float*)d_out;
    float* outE = outW + (size_t)B_ * T1_ * D_;

    // Probe first (racy, garbage output), REAL kernel last (correct output).
    enc_k<1, 3><<<dim3(B_ / MB_), dim3(512), 0, stream>>>(in, Wih, Whh, bih, bhh, aw, outW, outE);
    enc_k<0, 1><<<dim3(B_ / MB_), dim3(512), 0, stream>>>(in, Wih, Whh, bih, bhh, aw, outW, outE);
}

// Round 19
// 53.716 us; speedup vs baseline: 2.7406x; 2.7406x over previous
//
#include <hip/hip_runtime.h>

#define B_   2048
#define T1_  31
#define D_   128
#define MB_  8

typedef __attribute__((ext_vector_type(8))) short bf16x8;
typedef __attribute__((ext_vector_type(4))) float f32x4;
typedef __attribute__((ext_vector_type(2))) float f32x2;

__device__ __forceinline__ unsigned cvt_pk_bf16(float lo, float hi) {
    unsigned r;
    asm("v_cvt_pk_bf16_f32 %0, %1, %2" : "=v"(r) : "v"(lo), "v"(hi));
    return r;
}
__device__ __forceinline__ float rcpf_(float x) { return __builtin_amdgcn_rcpf(x); }
__device__ __forceinline__ float sigf(float x)  { return rcpf_(1.0f + __expf(-x)); }
__device__ __forceinline__ float tanhf_(float x) {
    float ax = fabsf(x);
    float t  = 1.0f - 2.0f * rcpf_(__expf(2.0f * ax) + 1.0f);
    return copysignf(t, x);
}

#define BAR_LDS() asm volatile("s_waitcnt lgkmcnt(0)\n\ts_barrier" ::: "memory")

// 256 blocks x 512 threads; block owns 8 batches for all 31 steps.
// Wave wv owns gate columns { s*128 + wv*16 + (lane&15) : s=0..3 }.
// Step window (R15-proven): [bar] -> ds_read hfr -> h-MFMA 4-chain seeded with
// carried accx(t) -> issue wx frags(t+2) ds_reads -> accx(t+1) MFMAs from
// RESIDENT wxn (no lgkm wait; latency hides under EW) -> EW -> h ds_write ->
// NT global stores (stay in flight) -> [bar, LDS-only].
__global__ __launch_bounds__(512, 2) void enc_fused(
    const float* __restrict__ in,    // [B][31][128]
    const float* __restrict__ Wih,   // [512][128]
    const float* __restrict__ Whh,   // [512][128]
    const float* __restrict__ bih,   // [512]
    const float* __restrict__ bhh,   // [512]
    const float* __restrict__ aw,    // [287]
    float* __restrict__ outW,        // [B][31][128]
    float* __restrict__ outE)        // [B][31][128]
{
    const int tid  = threadIdx.x;
    const int lane = tid & 63;
    const int wv   = tid >> 6;        // wave 0..7
    const int b0   = blockIdx.x * MB_;
    const int l15  = lane & 15;
    const int lq   = lane >> 4;

    __shared__ __align__(16) char Xw[30 * MB_ * 256];   // wx slots, 61440 B
    __shared__ __align__(16) char Hs[2 * MB_ * 256];    // h dbuf, 4096 B

    // ---------------- weight fragments -> registers ----------------------------
    bf16x8 bw[4][8];
    #pragma unroll
    for (int s = 0; s < 4; ++s) {
        int n = s * 128 + wv * 16 + l15;
        #pragma unroll
        for (int kf = 0; kf < 8; ++kf) {
            int kb = kf * 32 + lq * 8;
            const float* wp = (kf < 4) ? (Wih + n * D_ + kb) : (Whh + n * D_ + (kb - 128));
            float4 fa = *(const float4*)(wp);
            float4 fb = *(const float4*)(wp + 4);
            union { bf16x8 v; unsigned u[4]; } tmp;
            tmp.u[0] = cvt_pk_bf16(fa.x, fa.y);
            tmp.u[1] = cvt_pk_bf16(fa.z, fa.w);
            tmp.u[2] = cvt_pk_bf16(fb.x, fb.y);
            tmp.u[3] = cvt_pk_bf16(fb.z, fb.w);
            bw[s][kf] = tmp.v;
        }
    }
    const int col = wv * 16 + l15;
    const float bsv[4] = { bih[col]         + bhh[col],
                           bih[128 + col]   + bhh[128 + col],
                           bih[256 + col]   + bhh[256 + col],
                           bih[384 + col]   + bhh[384 + col] };

    // ---------------- pre-phase: x_score + pure-shfl softmax (row == wave) -----
    const int mg = wv;
    const int d0 = 2 * lane;
    const float* pin = in + (size_t)(b0 + mg) * (T1_ * D_) + d0;

    float2 xc[T1_];                    // input column-pair cached in registers
    float xs0 = 0.f, xs1 = 0.f;
    #pragma unroll
    for (int t = 0; t < T1_; ++t) {
        float wt = aw[2 * D_ + t];
        xc[t] = *(const float2*)(pin + t * D_);
        xs0 = fmaf(wt, xc[t].x, xs0);
        xs1 = fmaf(wt, xc[t].y, xs1);
    }
    float mx = fmaxf(xs0, xs1);
    #pragma unroll
    for (int o = 32; o > 0; o >>= 1) mx = fmaxf(mx, __shfl_xor(mx, o));
    float e0 = __expf(xs0 - mx), e1 = __expf(xs1 - mx);
    float ss = e0 + e1;
    #pragma unroll
    for (int o = 32; o > 0; o >>= 1) ss += __shfl_xor(ss, o);
    float inv = 1.0f / ss;
    const float a0 = e0 * inv;
    const float a1 = e1 * inv;

    // ---------------- wx staging: outW (NT) + Xw (swizzled bf16) ---------------
    const int wxbyte = (4 * lane) ^ (mg << 4);
    float* outWp = outW + (size_t)(b0 + mg) * (T1_ * D_) + d0;
    unsigned wx30 = 0;
    #pragma unroll
    for (int t = 0; t < T1_; ++t) {
        float w0 = a0 * xc[t].x, w1 = a1 * xc[t].y;
        f32x2 wsv; wsv[0] = w0; wsv[1] = w1;
        __builtin_nontemporal_store(wsv, (f32x2*)(outWp + t * D_));
        unsigned u = cvt_pk_bf16(w0, w1);
        if (t < 30) *(unsigned*)(Xw + t * 2048 + mg * 256 + wxbyte) = u;
        else        wx30 = u;
    }
    ((unsigned*)Hs)[tid]       = 0u;   // h(0) = 0, both buffers
    ((unsigned*)Hs)[tid + 512] = 0u;
    BAR_LDS();                         // staging visible; global stores in flight

    // ---------------- recurrent loop -------------------------------------------
    const int arow = l15 & 7;          // A-frag row (rows 8-15 replicate 0-7)
    const int asw  = arow << 4;
    const int rb   = ((lane & 31) >> 4) * 4 + ((lane >> 5) << 1);
    const bool hi32 = (lane >= 32);
    float* outE0 = outE + (size_t)(b0 + rb)     * (T1_ * D_) + col;
    float* outE1 = outE + (size_t)(b0 + rb + 1) * (T1_ * D_) + col;

    float cs0 = 0.f, cs1 = 0.f;
    f32x4 accx[4];
    bf16x8 wxn[4];
    {   // prologue: accx for t=0; issue wxn = frags(t=1)
        bf16x8 w0[4];
        #pragma unroll
        for (int kf = 0; kf < 4; ++kf)
            w0[kf] = *(const bf16x8*)(Xw + arow * 256 + ((kf * 64 + lq * 16) ^ asw));
        #pragma unroll
        for (int s = 0; s < 4; ++s) {
            float b = bsv[s];
            f32x4 aA = {b, b, b, b};
            #pragma unroll
            for (int kf = 0; kf < 4; ++kf)
                aA = __builtin_amdgcn_mfma_f32_16x16x32_bf16(w0[kf], bw[s][kf], aA, 0, 0, 0);
            accx[s] = aA;
        }
        #pragma unroll
        for (int kf = 0; kf < 4; ++kf)
            wxn[kf] = *(const bf16x8*)(Xw + 2048 + arow * 256 + ((kf * 64 + lq * 16) ^ asw));
    }

    for (int t = 0; t < T1_; ++t) {
        // h fragments for this step
        const char* hp = Hs + (t & 1) * 2048 + arow * 256;
        bf16x8 hfr[4];
        #pragma unroll
        for (int kf = 0; kf < 4; ++kf)
            hfr[kf] = *(const bf16x8*)(hp + ((kf * 64 + lq * 16) ^ asw));

        // gates = accx(t) [carried] + h @ Whh^T (4-deep seeded chain)
        f32x4 acc[4];
        #pragma unroll
        for (int s = 0; s < 4; ++s) {
            f32x4 a_ = accx[s];
            #pragma unroll
            for (int kf = 0; kf < 4; ++kf)
                a_ = __builtin_amdgcn_mfma_f32_16x16x32_bf16(hfr[kf], bw[s][4 + kf], a_, 0, 0, 0);
            acc[s] = a_;
        }

        // depth-2 prefetch: issue frags(t+2) ds_reads (drain during EW below)
        bf16x8 wxn2[4];
        if (t < 29) {
            int slot = (t + 2 == 30) ? 0 : (t + 2);
            const char* wn = Xw + slot * 2048 + arow * 256;
            #pragma unroll
            for (int kf = 0; kf < 4; ++kf)
                wxn2[kf] = *(const bf16x8*)(wn + ((kf * 64 + lq * 16) ^ asw));
        }
        if (t == 1)   // recycle slot 0 with wx[30]; t=0 reads done at barrier(0)
            *(unsigned*)(Xw + mg * 256 + wxbyte) = wx30;

        // accx(t+1): wxn already resident (no lgkm wait) -> MFMA latency hides
        // under the elementwise VALU work that follows.
        if (t < 30) {
            #pragma unroll
            for (int s = 0; s < 4; ++s) {
                float b = bsv[s];
                f32x4 aA = {b, b, b, b};
                #pragma unroll
                for (int kf = 0; kf < 4; ++kf)
                    aA = __builtin_amdgcn_mfma_f32_16x16x32_bf16(wxn[kf], bw[s][kf], aA, 0, 0, 0);
                accx[s] = aA;
            }
        }

        // row select via replication: lanes>=32 hold rows rb,rb+1 in acc[2],acc[3]
        float gq0[4], gq1[4];
        #pragma unroll
        for (int s = 0; s < 4; ++s) {
            gq0[s] = hi32 ? acc[s][2] : acc[s][0];
            gq1[s] = hi32 ? acc[s][3] : acc[s][1];
        }

        // elementwise, two independent cells interleaved
        float sf0 = sigf(gq0[1]), sf1 = sigf(gq1[1]);
        float si0 = sigf(gq0[0]), si1 = sigf(gq1[0]);
        float tg0 = tanhf_(gq0[2]), tg1 = tanhf_(gq1[2]);
        float so0 = sigf(gq0[3]), so1 = sigf(gq1[3]);
        float cn0 = sf0 * cs0 + si0 * tg0;  cs0 = cn0;
        float cn1 = sf1 * cs1 + si1 * tg1;  cs1 = cn1;
        float hh0 = so0 * tanhf_(cn0);
        float hh1 = so1 * tanhf_(cn1);
        unsigned hu = cvt_pk_bf16(hh0, hh1);

        // h LDS write (gates barrier); global NT stores after (don't gate)
        if (t < 30) {
            char* hw = Hs + ((t + 1) & 1) * 2048;
            *(unsigned short*)(hw + rb * 256       + ((2 * col) ^ (rb << 4)))       = (unsigned short)(hu & 0xffffu);
            *(unsigned short*)(hw + (rb + 1) * 256 + ((2 * col) ^ ((rb + 1) << 4))) = (unsigned short)(hu >> 16);
        }
        __builtin_nontemporal_store(hh0, outE0 + t * D_);
        __builtin_nontemporal_store(hh1, outE1 + t * D_);

        if (t < 29) {
            #pragma unroll
            for (int kf = 0; kf < 4; ++kf) wxn[kf] = wxn2[kf];
        }

        BAR_LDS();   // LDS-only visibility; global ops stay in flight
    }
}

extern "C" void kernel_launch(void* const* d_in, const int* in_sizes, int n_in,
                              void* d_out, int out_size, void* d_ws, size_t ws_size,
                              hipStream_t stream) {
    const float* in  = (const float*)d_in[0];
    const float* Wih = (const float*)d_in[1];
    const float* Whh = (const float*)d_in[2];
    const float* bih = (const float*)d_in[3];
    const float* bhh = (const float*)d_in[4];
    const float* aw  = (const float*)d_in[5];
    // d_in[6] (attn_b) is mathematically dead: softmax is shift-invariant.

    float* outW = (float*)d_out;
    float* outE = outW + (size_t)B_ * T1_ * D_;

    enc_fused<<<dim3(B_ / MB_), dim3(512), 0, stream>>>(in, Wih, Whh, bih, bhh, aw, outW, outE);
}

// Round 22
// 46.696 us; speedup vs baseline: 3.1527x; 1.1503x over previous
//
#include <hip/hip_runtime.h>

#define B_   2048
#define T1_  31
#define D_   128
#define MB_  8
#define XWSZ 61440

typedef __attribute__((ext_vector_type(8))) short bf16x8;
typedef __attribute__((ext_vector_type(4))) float f32x4;
typedef __attribute__((ext_vector_type(2))) float f32x2;

#define L2E  1.4426950408889634f
#define L2E2 2.8853900817779268f

__device__ __forceinline__ unsigned cvt_pk_bf16(float lo, float hi) {
    unsigned r;
    asm("v_cvt_pk_bf16_f32 %0, %1, %2" : "=v"(r) : "v"(lo), "v"(hi));
    return r;
}
__device__ __forceinline__ float rcpf_(float x)  { return __builtin_amdgcn_rcpf(x); }
__device__ __forceinline__ float exp2f_(float x) { return __builtin_amdgcn_exp2f(x); }
// inputs pre-scaled by log2e: sig(x) = rcp(1 + 2^-x'); neg folds into v_exp modifier
__device__ __forceinline__ float sg(float xp)  { return rcpf_(1.0f + exp2f_(-xp)); }
// y = 2*log2e*x: tanh(x) = 1 - 2*rcp(1 + 2^y); saturates correctly at +-inf
__device__ __forceinline__ float th2(float y)  { return fmaf(-2.0f, rcpf_(1.0f + exp2f_(y)), 1.0f); }

#define BAR_LDS() asm volatile("s_waitcnt lgkmcnt(0)\n\ts_barrier" ::: "memory")

// 256 blocks x 512 threads; block owns 8 batches for all 31 steps.
// R15 window + full 31-step unroll: all LDS accesses become fixed vaddr +
// constant offset immediates (single shared block: Xw=L[0..61440), Hs above),
// wxn copies become SSA renames, slot/parity arithmetic folds away.
// Weights prescaled by log2e (2*log2e for g-section) -> EW uses raw v_exp/v_rcp.
__global__ __launch_bounds__(512, 2) void enc_fused(
    const float* __restrict__ in,    // [B][31][128]
    const float* __restrict__ Wih,   // [512][128]
    const float* __restrict__ Whh,   // [512][128]
    const float* __restrict__ bih,   // [512]
    const float* __restrict__ bhh,   // [512]
    const float* __restrict__ aw,    // [287]
    float* __restrict__ outW,        // [B][31][128]
    float* __restrict__ outE)        // [B][31][128]
{
    const int tid  = threadIdx.x;
    const int lane = tid & 63;
    const int wv   = tid >> 6;        // wave 0..7
    const int b0   = blockIdx.x * MB_;
    const int l15  = lane & 15;
    const int lq   = lane >> 4;

    __shared__ __align__(16) char L[XWSZ + 4096];   // [0,61440): wx slots; above: h dbuf

    // ---------------- weight fragments -> registers (prescaled) ----------------
    bf16x8 bw[4][8];
    #pragma unroll
    for (int s = 0; s < 4; ++s) {
        const float scl = (s == 2) ? L2E2 : L2E;    // g-gate section gets 2*log2e
        int n = s * 128 + wv * 16 + l15;
        #pragma unroll
        for (int kf = 0; kf < 8; ++kf) {
            int kb = kf * 32 + lq * 8;
            const float* wp = (kf < 4) ? (Wih + n * D_ + kb) : (Whh + n * D_ + (kb - 128));
            float4 fa = *(const float4*)(wp);
            float4 fb = *(const float4*)(wp + 4);
            union { bf16x8 v; unsigned u[4]; } tmp;
            tmp.u[0] = cvt_pk_bf16(fa.x * scl, fa.y * scl);
            tmp.u[1] = cvt_pk_bf16(fa.z * scl, fa.w * scl);
            tmp.u[2] = cvt_pk_bf16(fb.x * scl, fb.y * scl);
            tmp.u[3] = cvt_pk_bf16(fb.z * scl, fb.w * scl);
            bw[s][kf] = tmp.v;
        }
    }
    const int col = wv * 16 + l15;
    const float bsv[4] = { (bih[col]       + bhh[col])       * L2E,
                           (bih[128 + col] + bhh[128 + col]) * L2E,
                           (bih[256 + col] + bhh[256 + col]) * L2E2,
                           (bih[384 + col] + bhh[384 + col]) * L2E };

    // ---------------- pre-phase: x_score + pure-shfl softmax (row == wave) -----
    const int mg = wv;
    const int d0 = 2 * lane;
    const float* pin = in + (size_t)(b0 + mg) * (T1_ * D_) + d0;

    float2 xc[T1_];
    float xs0 = 0.f, xs1 = 0.f;
    #pragma unroll
    for (int t = 0; t < T1_; ++t) {
        float wt = aw[2 * D_ + t];
        xc[t] = *(const float2*)(pin + t * D_);
        xs0 = fmaf(wt, xc[t].x, xs0);
        xs1 = fmaf(wt, xc[t].y, xs1);
    }
    float mx = fmaxf(xs0, xs1);
    #pragma unroll
    for (int o = 32; o > 0; o >>= 1) mx = fmaxf(mx, __shfl_xor(mx, o));
    float e0 = __expf(xs0 - mx), e1 = __expf(xs1 - mx);
    float ss = e0 + e1;
    #pragma unroll
    for (int o = 32; o > 0; o >>= 1) ss += __shfl_xor(ss, o);
    float inv = 1.0f / ss;
    const float a0 = e0 * inv;
    const float a1 = e1 * inv;

    // ---------------- wx staging: outW (NT) + L (swizzled bf16) ----------------
    const int wxbyte = (4 * lane) ^ (mg << 4);
    float* outWp = outW + (size_t)(b0 + mg) * (T1_ * D_) + d0;
    unsigned wx30 = 0;
    #pragma unroll
    for (int t = 0; t < T1_; ++t) {
        float w0 = a0 * xc[t].x, w1 = a1 * xc[t].y;
        f32x2 wsv; wsv[0] = w0; wsv[1] = w1;
        __builtin_nontemporal_store(wsv, (f32x2*)(outWp + t * D_));
        unsigned u = cvt_pk_bf16(w0, w1);
        if (t < 30) *(unsigned*)(L + t * 2048 + mg * 256 + wxbyte) = u;
        else        wx30 = u;
    }
    ((unsigned*)(L + XWSZ))[tid]       = 0u;   // h(0) = 0, both buffers
    ((unsigned*)(L + XWSZ))[tid + 512] = 0u;
    BAR_LDS();

    // ---------------- fixed per-lane LDS vaddrs --------------------------------
    const int arow = l15 & 7;          // A-frag row (rows 8-15 replicate 0-7)
    const int asw  = arow << 4;
    const char* vb[4];
    #pragma unroll
    for (int kf = 0; kf < 4; ++kf)
        vb[kf] = L + arow * 256 + ((kf * 64 + lq * 16) ^ asw);
    // wx slot s:   vb[kf] + s*2048          (imm <= 59392)
    // hfr (t):     vb[kf] + XWSZ + (t&1)*2048   (imm <= 63488)

    const int rb   = ((lane & 31) >> 4) * 4 + ((lane >> 5) << 1);
    const bool hi32 = (lane >= 32);
    const int wb0 = rb * 256       + ((2 * col) ^ (rb << 4));
    const int wb1 = (rb + 1) * 256 + ((2 * col) ^ ((rb + 1) << 4));
    float* outE0 = outE + (size_t)(b0 + rb)     * (T1_ * D_) + col;
    float* outE1 = outE + (size_t)(b0 + rb + 1) * (T1_ * D_) + col;

    float cs0 = 0.f, cs1 = 0.f;
    f32x4 accx[4];
    bf16x8 wxn[4];
    {   // prologue: accx for t=0; wxn = frags(t=1)
        bf16x8 w0[4];
        #pragma unroll
        for (int kf = 0; kf < 4; ++kf)
            w0[kf] = *(const bf16x8*)(vb[kf]);
        #pragma unroll
        for (int s = 0; s < 4; ++s) {
            float b = bsv[s];
            f32x4 aA = {b, b, b, b};
            #pragma unroll
            for (int kf = 0; kf < 4; ++kf)
                aA = __builtin_amdgcn_mfma_f32_16x16x32_bf16(w0[kf], bw[s][kf], aA, 0, 0, 0);
            accx[s] = aA;
        }
        #pragma unroll
        for (int kf = 0; kf < 4; ++kf)
            wxn[kf] = *(const bf16x8*)(vb[kf] + 2048);
    }

    #pragma unroll
    for (int t = 0; t < T1_; ++t) {
        // h fragments for this step (constant offset under unroll)
        bf16x8 hfr[4];
        #pragma unroll
        for (int kf = 0; kf < 4; ++kf)
            hfr[kf] = *(const bf16x8*)(vb[kf] + XWSZ + (t & 1) * 2048);

        // gates = accx(t) [carried] + h @ Whh^T (4-deep seeded chain)
        f32x4 acc[4];
        #pragma unroll
        for (int s = 0; s < 4; ++s) {
            f32x4 a_ = accx[s];
            #pragma unroll
            for (int kf = 0; kf < 4; ++kf)
                a_ = __builtin_amdgcn_mfma_f32_16x16x32_bf16(hfr[kf], bw[s][4 + kf], a_, 0, 0, 0);
            acc[s] = a_;
        }

        // depth-2 prefetch: frags(t+2); constant slot under unroll
        bf16x8 wxn2[4];
        if (t < 29) {
            const int slot = (t + 2 == 30) ? 0 : (t + 2);
            #pragma unroll
            for (int kf = 0; kf < 4; ++kf)
                wxn2[kf] = *(const bf16x8*)(vb[kf] + slot * 2048);
        }
        if (t == 1)   // recycle slot 0 with wx[30]; t=0 reads done at barrier(0)
            *(unsigned*)(L + mg * 256 + wxbyte) = wx30;

        // accx(t+1) from resident wxn: MFMA latency hides under EW below
        if (t < 30) {
            #pragma unroll
            for (int s = 0; s < 4; ++s) {
                float b = bsv[s];
                f32x4 aA = {b, b, b, b};
                #pragma unroll
                for (int kf = 0; kf < 4; ++kf)
                    aA = __builtin_amdgcn_mfma_f32_16x16x32_bf16(wxn[kf], bw[s][kf], aA, 0, 0, 0);
                accx[s] = aA;
            }
        }

        // row select via replication
        float gq0[4], gq1[4];
        #pragma unroll
        for (int s = 0; s < 4; ++s) {
            gq0[s] = hi32 ? acc[s][2] : acc[s][0];
            gq1[s] = hi32 ? acc[s][3] : acc[s][1];
        }

        // elementwise (prescaled): 2 independent cells
        float si0 = sg(gq0[0]), si1 = sg(gq1[0]);
        float sf0 = sg(gq0[1]), sf1 = sg(gq1[1]);
        float tg0 = th2(gq0[2]), tg1 = th2(gq1[2]);   // g pre-scaled by 2*log2e
        float so0 = sg(gq0[3]), so1 = sg(gq1[3]);
        float cn0 = fmaf(sf0, cs0, si0 * tg0);  cs0 = cn0;
        float cn1 = fmaf(sf1, cs1, si1 * tg1);  cs1 = cn1;
        float hh0 = so0 * th2(cn0 * L2E2);
        float hh1 = so1 * th2(cn1 * L2E2);
        unsigned hu = cvt_pk_bf16(hh0, hh1);

        // h LDS write (gates barrier); global NT stores after (don't gate)
        if (t < 30) {
            char* hw = L + XWSZ + (((t + 1) & 1) * 2048);
            *(unsigned short*)(hw + wb0) = (unsigned short)(hu & 0xffffu);
            *(unsigned short*)(hw + wb1) = (unsigned short)(hu >> 16);
        }
        __builtin_nontemporal_store(hh0, outE0 + t * D_);
        __builtin_nontemporal_store(hh1, outE1 + t * D_);

        if (t < 29) {
            #pragma unroll
            for (int kf = 0; kf < 4; ++kf) wxn[kf] = wxn2[kf];   // SSA rename under unroll
        }

        BAR_LDS();   // LDS-only visibility; global ops stay in flight
    }
}

extern "C" void kernel_launch(void* const* d_in, const int* in_sizes, int n_in,
                              void* d_out, int out_size, void* d_ws, size_t ws_size,
                              hipStream_t stream) {
    const float* in  = (const float*)d_in[0];
    const float* Wih = (const float*)d_in[1];
    const float* Whh = (const float*)d_in[2];
    const float* bih = (const float*)d_in[3];
    const float* bhh = (const float*)d_in[4];
    const float* aw  = (const float*)d_in[5];
    // d_in[6] (attn_b) is mathematically dead: softmax is shift-invariant.

    float* outW = (float*)d_out;
    float* outE = outW + (size_t)B_ * T1_ * D_;

    enc_fused<<<dim3(B_ / MB_), dim3(512), 0, stream>>>(in, Wih, Whh, bih, bhh, aw, outW, outE);
}

// Round 23
// 46.195 us; speedup vs baseline: 3.1868x; 1.0108x over previous
//
#include <hip/hip_runtime.h>

#define B_   2048
#define T1_  31
#define D_   128
#define MB_  8
#define XWSZ 61440

typedef __attribute__((ext_vector_type(8))) short bf16x8;
typedef __attribute__((ext_vector_type(4))) float f32x4;
typedef __attribute__((ext_vector_type(2))) float f32x2;

#define L2E  1.4426950408889634f
#define L2E2 2.8853900817779268f

__device__ __forceinline__ unsigned cvt_pk_bf16(float lo, float hi) {
    unsigned r;
    asm("v_cvt_pk_bf16_f32 %0, %1, %2" : "=v"(r) : "v"(lo), "v"(hi));
    return r;
}
__device__ __forceinline__ float rcpf_(float x)  { return __builtin_amdgcn_rcpf(x); }
__device__ __forceinline__ float exp2f_(float x) { return __builtin_amdgcn_exp2f(x); }
// inputs pre-scaled by log2e: sig(x) = rcp(1 + 2^-x'); neg folds into v_exp modifier
__device__ __forceinline__ float sg(float xp)  { return rcpf_(1.0f + exp2f_(-xp)); }
// y = 2*log2e*x: tanh(x) = 1 - 2*rcp(1 + 2^y); saturates correctly at +-inf
__device__ __forceinline__ float th2(float y)  { return fmaf(-2.0f, rcpf_(1.0f + exp2f_(y)), 1.0f); }

#define BAR_LDS() asm volatile("s_waitcnt lgkmcnt(0)\n\ts_barrier" ::: "memory")

// 256 blocks x 512 threads; block owns 8 batches for all 31 steps.
// R15 window + full 31-step unroll + fixed-vaddr LDS addressing + exp2 EW.
// Pre-phase issues the 31 HBM x-loads FIRST (longest latency), then the L3
// weight loads; xs/softmax consume xc after both streams are in flight.
__global__ __launch_bounds__(512, 2) void enc_fused(
    const float* __restrict__ in,    // [B][31][128]
    const float* __restrict__ Wih,   // [512][128]
    const float* __restrict__ Whh,   // [512][128]
    const float* __restrict__ bih,   // [512]
    const float* __restrict__ bhh,   // [512]
    const float* __restrict__ aw,    // [287]
    float* __restrict__ outW,        // [B][31][128]
    float* __restrict__ outE)        // [B][31][128]
{
    const int tid  = threadIdx.x;
    const int lane = tid & 63;
    const int wv   = tid >> 6;        // wave 0..7
    const int b0   = blockIdx.x * MB_;
    const int l15  = lane & 15;
    const int lq   = lane >> 4;

    __shared__ __align__(16) char L[XWSZ + 4096];   // [0,61440): wx slots; above: h dbuf

    // ---------------- issue x loads first (HBM, longest latency) ---------------
    const int mg = wv;
    const int d0 = 2 * lane;
    const float* pin = in + (size_t)(b0 + mg) * (T1_ * D_) + d0;
    float2 xc[T1_];
    #pragma unroll
    for (int t = 0; t < T1_; ++t)
        xc[t] = *(const float2*)(pin + t * D_);

    // ---------------- weight fragments -> registers (prescaled, L3-hot) --------
    bf16x8 bw[4][8];
    #pragma unroll
    for (int s = 0; s < 4; ++s) {
        const float scl = (s == 2) ? L2E2 : L2E;    // g-gate section gets 2*log2e
        int n = s * 128 + wv * 16 + l15;
        #pragma unroll
        for (int kf = 0; kf < 8; ++kf) {
            int kb = kf * 32 + lq * 8;
            const float* wp = (kf < 4) ? (Wih + n * D_ + kb) : (Whh + n * D_ + (kb - 128));
            float4 fa = *(const float4*)(wp);
            float4 fb = *(const float4*)(wp + 4);
            union { bf16x8 v; unsigned u[4]; } tmp;
            tmp.u[0] = cvt_pk_bf16(fa.x * scl, fa.y * scl);
            tmp.u[1] = cvt_pk_bf16(fa.z * scl, fa.w * scl);
            tmp.u[2] = cvt_pk_bf16(fb.x * scl, fb.y * scl);
            tmp.u[3] = cvt_pk_bf16(fb.z * scl, fb.w * scl);
            bw[s][kf] = tmp.v;
        }
    }
    const int col = wv * 16 + l15;
    const float bsv[4] = { (bih[col]       + bhh[col])       * L2E,
                           (bih[128 + col] + bhh[128 + col]) * L2E,
                           (bih[256 + col] + bhh[256 + col]) * L2E2,
                           (bih[384 + col] + bhh[384 + col]) * L2E };

    // ---------------- x_score + pure-shfl softmax (exp2) -----------------------
    float xs0 = 0.f, xs1 = 0.f;
    #pragma unroll
    for (int t = 0; t < T1_; ++t) {
        float wt = aw[2 * D_ + t];
        xs0 = fmaf(wt, xc[t].x, xs0);
        xs1 = fmaf(wt, xc[t].y, xs1);
    }
    float mx = fmaxf(xs0, xs1);
    #pragma unroll
    for (int o = 32; o > 0; o >>= 1) mx = fmaxf(mx, __shfl_xor(mx, o));
    float e0 = exp2f_((xs0 - mx) * L2E), e1 = exp2f_((xs1 - mx) * L2E);
    float ss = e0 + e1;
    #pragma unroll
    for (int o = 32; o > 0; o >>= 1) ss += __shfl_xor(ss, o);
    float inv = 1.0f / ss;
    const float a0 = e0 * inv;
    const float a1 = e1 * inv;

    // ---------------- wx staging: outW (NT) + L (swizzled bf16) ----------------
    const int wxbyte = (4 * lane) ^ (mg << 4);
    float* outWp = outW + (size_t)(b0 + mg) * (T1_ * D_) + d0;
    unsigned wx30 = 0;
    #pragma unroll
    for (int t = 0; t < T1_; ++t) {
        float w0 = a0 * xc[t].x, w1 = a1 * xc[t].y;
        f32x2 wsv; wsv[0] = w0; wsv[1] = w1;
        __builtin_nontemporal_store(wsv, (f32x2*)(outWp + t * D_));
        unsigned u = cvt_pk_bf16(w0, w1);
        if (t < 30) *(unsigned*)(L + t * 2048 + mg * 256 + wxbyte) = u;
        else        wx30 = u;
    }
    ((unsigned*)(L + XWSZ))[tid]       = 0u;   // h(0) = 0, both buffers
    ((unsigned*)(L + XWSZ))[tid + 512] = 0u;
    BAR_LDS();

    // ---------------- fixed per-lane LDS vaddrs --------------------------------
    const int arow = l15 & 7;          // A-frag row (rows 8-15 replicate 0-7)
    const int asw  = arow << 4;
    const char* vb[4];
    #pragma unroll
    for (int kf = 0; kf < 4; ++kf)
        vb[kf] = L + arow * 256 + ((kf * 64 + lq * 16) ^ asw);
    // wx slot s:   vb[kf] + s*2048              (imm <= 59392)
    // hfr (t):     vb[kf] + XWSZ + (t&1)*2048   (imm <= 63488)

    const int rb   = ((lane & 31) >> 4) * 4 + ((lane >> 5) << 1);
    const bool hi32 = (lane >= 32);
    const int wb0 = rb * 256       + ((2 * col) ^ (rb << 4));
    const int wb1 = (rb + 1) * 256 + ((2 * col) ^ ((rb + 1) << 4));
    float* outE0 = outE + (size_t)(b0 + rb)     * (T1_ * D_) + col;
    float* outE1 = outE + (size_t)(b0 + rb + 1) * (T1_ * D_) + col;

    float cs0 = 0.f, cs1 = 0.f;
    f32x4 accx[4];
    bf16x8 wxn[4];
    {   // prologue: accx for t=0; wxn = frags(t=1)
        bf16x8 w0[4];
        #pragma unroll
        for (int kf = 0; kf < 4; ++kf)
            w0[kf] = *(const bf16x8*)(vb[kf]);
        #pragma unroll
        for (int s = 0; s < 4; ++s) {
            float b = bsv[s];
            f32x4 aA = {b, b, b, b};
            #pragma unroll
            for (int kf = 0; kf < 4; ++kf)
                aA = __builtin_amdgcn_mfma_f32_16x16x32_bf16(w0[kf], bw[s][kf], aA, 0, 0, 0);
            accx[s] = aA;
        }
        #pragma unroll
        for (int kf = 0; kf < 4; ++kf)
            wxn[kf] = *(const bf16x8*)(vb[kf] + 2048);
    }

    #pragma unroll
    for (int t = 0; t < T1_; ++t) {
        // h fragments for this step (constant offset under unroll)
        bf16x8 hfr[4];
        #pragma unroll
        for (int kf = 0; kf < 4; ++kf)
            hfr[kf] = *(const bf16x8*)(vb[kf] + XWSZ + (t & 1) * 2048);

        // gates = accx(t) [carried] + h @ Whh^T (4-deep seeded chain)
        f32x4 acc[4];
        #pragma unroll
        for (int s = 0; s < 4; ++s) {
            f32x4 a_ = accx[s];
            #pragma unroll
            for (int kf = 0; kf < 4; ++kf)
                a_ = __builtin_amdgcn_mfma_f32_16x16x32_bf16(hfr[kf], bw[s][4 + kf], a_, 0, 0, 0);
            acc[s] = a_;
        }

        // depth-2 prefetch: frags(t+2); constant slot under unroll
        bf16x8 wxn2[4];
        if (t < 29) {
            const int slot = (t + 2 == 30) ? 0 : (t + 2);
            #pragma unroll
            for (int kf = 0; kf < 4; ++kf)
                wxn2[kf] = *(const bf16x8*)(vb[kf] + slot * 2048);
        }
        if (t == 1)   // recycle slot 0 with wx[30]; t=0 reads done at barrier(0)
            *(unsigned*)(L + mg * 256 + wxbyte) = wx30;

        // accx(t+1) from resident wxn: MFMA latency hides under EW below
        if (t < 30) {
            #pragma unroll
            for (int s = 0; s < 4; ++s) {
                float b = bsv[s];
                f32x4 aA = {b, b, b, b};
                #pragma unroll
                for (int kf = 0; kf < 4; ++kf)
                    aA = __builtin_amdgcn_mfma_f32_16x16x32_bf16(wxn[kf], bw[s][kf], aA, 0, 0, 0);
                accx[s] = aA;
            }
        }

        // row select via replication
        float gq0[4], gq1[4];
        #pragma unroll
        for (int s = 0; s < 4; ++s) {
            gq0[s] = hi32 ? acc[s][2] : acc[s][0];
            gq1[s] = hi32 ? acc[s][3] : acc[s][1];
        }

        // elementwise (prescaled): 2 independent cells
        float si0 = sg(gq0[0]), si1 = sg(gq1[0]);
        float sf0 = sg(gq0[1]), sf1 = sg(gq1[1]);
        float tg0 = th2(gq0[2]), tg1 = th2(gq1[2]);   // g pre-scaled by 2*log2e
        float so0 = sg(gq0[3]), so1 = sg(gq1[3]);
        float cn0 = fmaf(sf0, cs0, si0 * tg0);  cs0 = cn0;
        float cn1 = fmaf(sf1, cs1, si1 * tg1);  cs1 = cn1;
        float hh0 = so0 * th2(cn0 * L2E2);
        float hh1 = so1 * th2(cn1 * L2E2);
        unsigned hu = cvt_pk_bf16(hh0, hh1);

        // h LDS write (gates barrier); global NT stores after (don't gate)
        if (t < 30) {
            char* hw = L + XWSZ + (((t + 1) & 1) * 2048);
            *(unsigned short*)(hw + wb0) = (unsigned short)(hu & 0xffffu);
            *(unsigned short*)(hw + wb1) = (unsigned short)(hu >> 16);
        }
        __builtin_nontemporal_store(hh0, outE0 + t * D_);
        __builtin_nontemporal_store(hh1, outE1 + t * D_);

        if (t < 29) {
            #pragma unroll
            for (int kf = 0; kf < 4; ++kf) wxn[kf] = wxn2[kf];   // SSA rename under unroll
        }

        BAR_LDS();   // LDS-only visibility; global ops stay in flight
    }
}

extern "C" void kernel_launch(void* const* d_in, const int* in_sizes, int n_in,
                              void* d_out, int out_size, void* d_ws, size_t ws_size,
                              hipStream_t stream) {
    const float* in  = (const float*)d_in[0];
    const float* Wih = (const float*)d_in[1];
    const float* Whh = (const float*)d_in[2];
    const float* bih = (const float*)d_in[3];
    const float* bhh = (const float*)d_in[4];
    const float* aw  = (const float*)d_in[5];
    // d_in[6] (attn_b) is mathematically dead: softmax is shift-invariant.

    float* outW = (float*)d_out;
    float* outE = outW + (size_t)B_ * T1_ * D_;

    enc_fused<<<dim3(B_ / MB_), dim3(512), 0, stream>>>(in, Wih, Whh, bih, bhh, aw, outW, outE);
}